// Round 1
// baseline (1529.706 us; speedup 1.0000x reference)
//
#include <hip/hip_runtime.h>
#include <cmath>

#define NNODES 20000
#define NEDGES 640000
#define DDIM   128
#define TE     32     // edges per block in edge kernel
#define TN     16     // nodes per block in qk kernel

// ---------------------------------------------------------------------------
// Kernel 1: q = node_feats @ Wq, k = node_feats @ Wk   (both [N,128] fp32)
// threads 0..127 compute q column j; threads 128..255 compute k column j.
// ---------------------------------------------------------------------------
__global__ __launch_bounds__(256) void qk_proj_kernel(
    const float* __restrict__ nf, const float* __restrict__ Wq,
    const float* __restrict__ Wk, float* __restrict__ qbuf,
    float* __restrict__ kbuf)
{
    __shared__ float s_nf[TN * DDIM];
    const int t  = threadIdx.x;
    const int n0 = blockIdx.x * TN;
    {
        const float4* src = (const float4*)(nf + (size_t)n0 * DDIM);
        float4* dst = (float4*)s_nf;
        for (int i = t; i < TN * DDIM / 4; i += 256) dst[i] = src[i];
    }
    __syncthreads();

    const int j = t & 127;
    const float* W = (t < 128) ? Wq : Wk;
    float acc[TN];
#pragma unroll
    for (int n = 0; n < TN; n++) acc[n] = 0.f;

    for (int k = 0; k < DDIM; k += 4) {
        const float w0 = W[(k + 0) * DDIM + j];
        const float w1 = W[(k + 1) * DDIM + j];
        const float w2 = W[(k + 2) * DDIM + j];
        const float w3 = W[(k + 3) * DDIM + j];
#pragma unroll
        for (int n = 0; n < TN; n++) {
            const float4 f = *(const float4*)&s_nf[n * DDIM + k];
            acc[n] = fmaf(f.w, w3, fmaf(f.z, w2, fmaf(f.y, w1, fmaf(f.x, w0, acc[n]))));
        }
    }
    float* outp = (t < 128) ? qbuf : kbuf;
    for (int n = 0; n < TN; n++) outp[(size_t)(n0 + n) * DDIM + j] = acc[n];
}

// ---------------------------------------------------------------------------
// Kernel 2: fused per-edge pipeline.
//   w = silu(ef@W_rad1+b)@W_rad2+b + silu(cs@W_sph1+b)@W_sph2+b   [TE,128]
//   alpha[e,h] = (q[recv] * w * k[send]).sum over head dims / sqrt(32) * cutoff
//   out[recv] += edge_sh * repeat(alpha, [1,3,5,7]) / 32
// ---------------------------------------------------------------------------
__global__ __launch_bounds__(256) void edge_kernel(
    const float* __restrict__ edge_sh, const float* __restrict__ edge_feats,
    const float* __restrict__ chi_scalar, const float* __restrict__ cutoffs,
    const int* __restrict__ senders, const int* __restrict__ receivers,
    const float* __restrict__ W_rad1, const float* __restrict__ b_rad1,
    const float* __restrict__ W_rad2, const float* __restrict__ b_rad2,
    const float* __restrict__ W_sph1, const float* __restrict__ b_sph1,
    const float* __restrict__ W_sph2, const float* __restrict__ b_sph2,
    const float* __restrict__ qbuf, const float* __restrict__ kbuf,
    float* __restrict__ out)
{
    __shared__ float s_in[TE * 64 * 2];   // phase A/B: [rad rows | sph rows]; phase C+: aliased as s_w [TE*128]
    __shared__ float s_h[TE * 256];       // hidden: [e][0..127]=silu rad, [e][128..255]=silu sph
    __shared__ float s_alpha[TE][4];

    const int t  = threadIdx.x;
    const int eb = blockIdx.x * TE;

    // ---- Phase A: stage edge inputs ----
    {
        const float4* src1 = (const float4*)(edge_feats + (size_t)eb * 64);
        const float4* src2 = (const float4*)(chi_scalar + (size_t)eb * 64);
        float4* d1 = (float4*)s_in;
        float4* d2 = (float4*)(s_in + TE * 64);
        for (int i = t; i < TE * 64 / 4; i += 256) { d1[i] = src1[i]; d2[i] = src2[i]; }
    }
    __syncthreads();

    const int j   = t & 127;
    const int grp = t >> 7;   // 0 = radial path, 1 = spherical path

    // ---- Phase B: layer 1 (K=64) + silu ----
    {
        const float* in = s_in + grp * (TE * 64);
        const float* W1 = grp ? W_sph1 : W_rad1;
        const float* b1 = grp ? b_sph1 : b_rad1;
        float acc[TE];
#pragma unroll
        for (int e = 0; e < TE; e++) acc[e] = 0.f;
        for (int k = 0; k < 64; k += 4) {
            const float w0 = W1[(k + 0) * 128 + j];
            const float w1 = W1[(k + 1) * 128 + j];
            const float w2 = W1[(k + 2) * 128 + j];
            const float w3 = W1[(k + 3) * 128 + j];
#pragma unroll
            for (int e = 0; e < TE; e++) {
                const float4 f = *(const float4*)&in[e * 64 + k];  // uniform addr per wave -> broadcast
                acc[e] = fmaf(f.w, w3, fmaf(f.z, w2, fmaf(f.y, w1, fmaf(f.x, w0, acc[e]))));
            }
        }
        const float bb = b1[j];
#pragma unroll
        for (int e = 0; e < TE; e++) {
            float v = acc[e] + bb;
            v = v / (1.0f + expf(-v));          // silu
            s_h[e * 256 + grp * 128 + j] = v;
        }
    }
    __syncthreads();

    // ---- Phase C: layer 2 (K=256 split: grp0 rad half, grp1 sph half) ----
    float* s_w = s_in;  // alias: s_in no longer needed
    {
        const float* W2   = grp ? W_sph2 : W_rad2;
        const int    koff = grp * 128;
        float acc[TE];
#pragma unroll
        for (int e = 0; e < TE; e++) acc[e] = 0.f;
        for (int k = 0; k < 128; k += 4) {
            const float w0 = W2[(k + 0) * 128 + j];
            const float w1 = W2[(k + 1) * 128 + j];
            const float w2 = W2[(k + 2) * 128 + j];
            const float w3 = W2[(k + 3) * 128 + j];
#pragma unroll
            for (int e = 0; e < TE; e++) {
                const float4 f = *(const float4*)&s_h[e * 256 + koff + k];
                acc[e] = fmaf(f.w, w3, fmaf(f.z, w2, fmaf(f.y, w1, fmaf(f.x, w0, acc[e]))));
            }
        }
        if (grp == 1) {
#pragma unroll
            for (int e = 0; e < TE; e++) s_w[e * 128 + j] = acc[e];
        }
        __syncthreads();
        if (grp == 0) {
            const float bb = b_rad2[j] + b_sph2[j];
#pragma unroll
            for (int e = 0; e < TE; e++) s_w[e * 128 + j] = s_w[e * 128 + j] + acc[e] + bb;
        }
    }
    __syncthreads();

    // ---- Phase D: alpha[e,h] = sum_d q*w*k / sqrt(32) * cutoff ----
    {
        const int e    = t >> 3;        // 32 edges
        const int sub  = t & 7;         // 8 threads/edge: 4 heads x 2 halves
        const int head = sub >> 1;
        const int part = sub & 1;
        const int eg   = eb + e;
        const int r    = receivers[eg];
        const int s    = senders[eg];
        const int dbase = head * 32 + part * 16;
        const float4* qp = (const float4*)(qbuf + (size_t)r * 128 + dbase);
        const float4* kp = (const float4*)(kbuf + (size_t)s * 128 + dbase);
        float sum = 0.f;
#pragma unroll
        for (int i = 0; i < 4; i++) {
            const float4 qv = qp[i];
            const float4 kv = kp[i];
            const float4 wv = *(const float4*)&s_w[e * 128 + dbase + i * 4];
            sum += qv.x * wv.x * kv.x + qv.y * wv.y * kv.y
                 + qv.z * wv.z * kv.z + qv.w * wv.w * kv.w;
        }
        sum += __shfl_xor(sum, 1, 64);  // combine the two 16-dim halves
        if (part == 0) {
            // 1/sqrt(32) * 1/32 = 0.005524271728019903
            s_alpha[e][head] = sum * cutoffs[eg] * 0.005524271728019903f;
        }
    }
    __syncthreads();

    // ---- Phase E: msg = edge_sh * repeat(alpha, [1,3,5,7]); scatter-add ----
    {
        const int e  = t >> 3;
        const int c0 = t & 7;
        const int eg = eb + e;
        const int r  = receivers[eg];
#pragma unroll
        for (int cc = 0; cc < 2; cc++) {
            const int m = c0 + cc * 8;
            const int head = (m == 0) ? 0 : (m < 4) ? 1 : (m < 9) ? 2 : 3;
            const float msg = edge_sh[(size_t)eg * 16 + m] * s_alpha[e][head];
            atomicAdd(&out[(size_t)r * 16 + m], msg);
        }
    }
}

// ---------------------------------------------------------------------------
extern "C" void kernel_launch(void* const* d_in, const int* in_sizes, int n_in,
                              void* d_out, int out_size, void* d_ws, size_t ws_size,
                              hipStream_t stream)
{
    const float* edge_sh    = (const float*)d_in[0];
    const float* node_feats = (const float*)d_in[1];
    const float* edge_feats = (const float*)d_in[2];
    const float* chi_scalar = (const float*)d_in[3];
    const float* cutoffs    = (const float*)d_in[4];
    const int*   senders    = (const int*)d_in[5];
    const int*   receivers  = (const int*)d_in[6];
    const float* W_rad1 = (const float*)d_in[7];
    const float* b_rad1 = (const float*)d_in[8];
    const float* W_rad2 = (const float*)d_in[9];
    const float* b_rad2 = (const float*)d_in[10];
    const float* W_sph1 = (const float*)d_in[11];
    const float* b_sph1 = (const float*)d_in[12];
    const float* W_sph2 = (const float*)d_in[13];
    const float* b_sph2 = (const float*)d_in[14];
    const float* Wq     = (const float*)d_in[15];
    const float* Wk     = (const float*)d_in[16];

    float* out  = (float*)d_out;
    float* qbuf = (float*)d_ws;                       // [N,128]
    float* kbuf = qbuf + (size_t)NNODES * DDIM;       // [N,128]

    hipMemsetAsync(out, 0, (size_t)out_size * sizeof(float), stream);

    qk_proj_kernel<<<NNODES / TN, 256, 0, stream>>>(node_feats, Wq, Wk, qbuf, kbuf);

    edge_kernel<<<NEDGES / TE, 256, 0, stream>>>(
        edge_sh, edge_feats, chi_scalar, cutoffs, senders, receivers,
        W_rad1, b_rad1, W_rad2, b_rad2, W_sph1, b_sph1, W_sph2, b_sph2,
        qbuf, kbuf, out);
}

// Round 2
// 311.040 us; speedup vs baseline: 4.9180x; 4.9180x over previous
//
#include <hip/hip_runtime.h>
#include <cmath>

#define NNODES 20000
#define NEDGES 640000
#define DDIM   128
#define TN     16    // nodes per block in qk kernel
#define BE     64    // edges per block in edge kernel

typedef __attribute__((ext_vector_type(8))) short bf16x8;
typedef __attribute__((ext_vector_type(4))) float f32x4;
typedef __attribute__((ext_vector_type(4))) unsigned short us4;

__device__ __forceinline__ unsigned short f2bf(float x) {
    union { float f; unsigned u; } v; v.f = x;
    unsigned r = v.u + 0x7FFFu + ((v.u >> 16) & 1u);   // RNE
    return (unsigned short)(r >> 16);
}
__device__ __forceinline__ float bf2f(unsigned short h) {
    union { unsigned u; float f; } v; v.u = ((unsigned)h) << 16; return v.f;
}

// ---------------------------------------------------------------------------
// Pack fp32 weight matrix [K x 128] into bf16 MFMA A-fragment layout.
// frame f = kt*8 + nt; elem (lane,i): W[kt*32 + (lane>>4)*8 + i][nt*16 + (lane&15)]
// grid = number of frames (K/32 * 8), block = 256.
// ---------------------------------------------------------------------------
__global__ void pack_weights(const float* __restrict__ W, unsigned short* __restrict__ dst)
{
    const int f  = blockIdx.x;
    const int kt = f >> 3, nt = f & 7;
    const int t  = threadIdx.x;
#pragma unroll
    for (int ii = 0; ii < 2; ii++) {
        const int idx  = t * 2 + ii;          // 0..511
        const int lane = idx >> 3, i = idx & 7;
        const int k = kt * 32 + (lane >> 4) * 8 + i;
        const int n = nt * 16 + (lane & 15);
        dst[f * 512 + idx] = f2bf(W[k * 128 + n]);
    }
}

// ---------------------------------------------------------------------------
// q = node_feats @ Wq, k = node_feats @ Wk  (fp32, unchanged from round 1)
// ---------------------------------------------------------------------------
__global__ __launch_bounds__(256) void qk_proj_kernel(
    const float* __restrict__ nf, const float* __restrict__ Wq,
    const float* __restrict__ Wk, float* __restrict__ qbuf,
    float* __restrict__ kbuf)
{
    __shared__ float s_nf[TN * DDIM];
    const int t  = threadIdx.x;
    const int n0 = blockIdx.x * TN;
    {
        const float4* src = (const float4*)(nf + (size_t)n0 * DDIM);
        float4* dst = (float4*)s_nf;
        for (int i = t; i < TN * DDIM / 4; i += 256) dst[i] = src[i];
    }
    __syncthreads();

    const int j = t & 127;
    const float* W = (t < 128) ? Wq : Wk;
    float acc[TN];
#pragma unroll
    for (int n = 0; n < TN; n++) acc[n] = 0.f;

    for (int k = 0; k < DDIM; k += 4) {
        const float w0 = W[(k + 0) * DDIM + j];
        const float w1 = W[(k + 1) * DDIM + j];
        const float w2 = W[(k + 2) * DDIM + j];
        const float w3 = W[(k + 3) * DDIM + j];
#pragma unroll
        for (int n = 0; n < TN; n++) {
            const float4 f = *(const float4*)&s_nf[n * DDIM + k];
            acc[n] = fmaf(f.w, w3, fmaf(f.z, w2, fmaf(f.y, w1, fmaf(f.x, w0, acc[n]))));
        }
    }
    float* outp = (t < 128) ? qbuf : kbuf;
    for (int n = 0; n < TN; n++) outp[(size_t)(n0 + n) * DDIM + j] = acc[n];
}

// ---------------------------------------------------------------------------
// Fused edge kernel, MFMA version. 64 edges/block, 4 waves, wave w = head w.
// mfma(W_frag(A), edge_frag(B)) -> C frag: lane holds edge (l&15 within tile),
// 4 consecutive output cols ((l>>4)*4 + reg).
// ---------------------------------------------------------------------------
__global__ __launch_bounds__(256) void edge_kernel(
    const float* __restrict__ edge_sh, const float* __restrict__ cutoffs,
    const int* __restrict__ senders, const int* __restrict__ receivers,
    const float* __restrict__ edge_feats, const float* __restrict__ chi_scalar,
    const unsigned short* __restrict__ w1r, const unsigned short* __restrict__ w1s,
    const unsigned short* __restrict__ w2r, const unsigned short* __restrict__ w2s,
    const float* __restrict__ b_rad1, const float* __restrict__ b_sph1,
    const float* __restrict__ b_rad2, const float* __restrict__ b_sph2,
    const float* __restrict__ qbuf, const float* __restrict__ kbuf,
    float* __restrict__ out)
{
    __shared__ unsigned short s_a[2 * 64 * 64];   // 16 KB  [path][edge][k] swizzled
    __shared__ unsigned short s_h[64 * 128];      // 16 KB  [edge][hid]    swizzled
    __shared__ unsigned short s_p[64 * 128];      // 16 KB  [edge][c]=q*k  swizzled
    __shared__ float s_alpha[64][4];              // 1 KB

    char* pa = (char*)s_a;
    char* ph = (char*)s_h;
    char* pp = (char*)s_p;

    const int t  = threadIdx.x;
    const int w  = t >> 6;        // wave id == head id
    const int l  = t & 63;
    const int eb = blockIdx.x * BE;

    // ---- Phase P: gather q,k rows; p = q*k -> bf16 LDS (swizzled) ----
#pragma unroll
    for (int ii = 0; ii < 8; ii++) {
        const int e  = w * 16 + ii * 2 + (l >> 5);
        const int eg = eb + e;
        const int r  = receivers[eg];
        const int s  = senders[eg];
        const int c4 = l & 31;
        const float4 qv = *(const float4*)(qbuf + (size_t)r * 128 + c4 * 4);
        const float4 kv = *(const float4*)(kbuf + (size_t)s * 128 + c4 * 4);
        us4 pv = { f2bf(qv.x * kv.x), f2bf(qv.y * kv.y),
                   f2bf(qv.z * kv.z), f2bf(qv.w * kv.w) };
        *(us4*)(pp + ((e * 256 + c4 * 8) ^ ((e & 7) << 4))) = pv;
    }

    // ---- Phase A: stage edge_feats & chi_scalar as bf16 (swizzled) ----
#pragma unroll
    for (int ii = 0; ii < 4; ii++) {
        const int idx = t + ii * 256;     // float4 index, 0..1023
        const int r   = idx >> 4;
        const int c4  = idx & 15;
        const float4 a = *(const float4*)(edge_feats + (size_t)(eb + r) * 64 + c4 * 4);
        const float4 b = *(const float4*)(chi_scalar + (size_t)(eb + r) * 64 + c4 * 4);
        us4 av = { f2bf(a.x), f2bf(a.y), f2bf(a.z), f2bf(a.w) };
        us4 bv = { f2bf(b.x), f2bf(b.y), f2bf(b.z), f2bf(b.w) };
        const int off = (r * 128 + c4 * 8) ^ ((r & 7) << 4);
        *(us4*)(pa + off)        = av;
        *(us4*)(pa + 8192 + off) = bv;
    }
    __syncthreads();

    f32x4 acc2[2][4];     // [ct][et] final w cols (both paths accumulate here)
#pragma unroll
    for (int ct = 0; ct < 2; ct++)
#pragma unroll
        for (int et = 0; et < 4; et++)
            acc2[ct][et] = (f32x4){0.f, 0.f, 0.f, 0.f};

    for (int path = 0; path < 2; path++) {
        const unsigned short* W1p = path ? w1s : w1r;
        const unsigned short* W2p = path ? w2s : w2r;
        const float* b1p = path ? b_sph1 : b_rad1;
        const char*  ab  = pa + path * 8192;

        // ---- Layer 1: this wave computes hid cols [w*32, w*32+32) for all 64 edges
        f32x4 acc1[2][4];
#pragma unroll
        for (int ht = 0; ht < 2; ht++)
#pragma unroll
            for (int et = 0; et < 4; et++)
                acc1[ht][et] = (f32x4){0.f, 0.f, 0.f, 0.f};

#pragma unroll
        for (int kt = 0; kt < 2; kt++) {
            bf16x8 bfrag[4];
#pragma unroll
            for (int et = 0; et < 4; et++) {
                const int e = et * 16 + (l & 15);
                const int k = kt * 32 + (l >> 4) * 8;
                bfrag[et] = *(const bf16x8*)(ab + ((e * 128 + k * 2) ^ ((e & 7) << 4)));
            }
#pragma unroll
            for (int ht = 0; ht < 2; ht++) {
                const int f = kt * 8 + (w * 2 + ht);
                const bf16x8 afrag = *(const bf16x8*)(W1p + (size_t)f * 512 + l * 8);
#pragma unroll
                for (int et = 0; et < 4; et++)
                    acc1[ht][et] = __builtin_amdgcn_mfma_f32_16x16x32_bf16(
                        afrag, bfrag[et], acc1[ht][et], 0, 0, 0);
            }
        }

        // bias + silu -> H (each wave writes its own hid-slice; no sync needed)
#pragma unroll
        for (int ht = 0; ht < 2; ht++) {
            const int hid0 = w * 32 + ht * 16 + (l >> 4) * 4;
            const float4 bv = *(const float4*)(b1p + hid0);
#pragma unroll
            for (int et = 0; et < 4; et++) {
                const int e = et * 16 + (l & 15);
                us4 hv;
#pragma unroll
                for (int r = 0; r < 4; r++) {
                    const float v = acc1[ht][et][r] + ((const float*)&bv)[r];
                    const float s = v / (1.0f + __expf(-v));
                    hv[r] = f2bf(s);
                }
                *(us4*)(ph + ((e * 256 + hid0 * 2) ^ ((e & 7) << 4))) = hv;
            }
        }
        __syncthreads();

        // ---- Layer 2: acc2 += W2[cols w*32..+32] @ H  (K = 128) ----
#pragma unroll
        for (int kt = 0; kt < 4; kt++) {
            bf16x8 hfrag[4];
#pragma unroll
            for (int et = 0; et < 4; et++) {
                const int e = et * 16 + (l & 15);
                const int k = kt * 32 + (l >> 4) * 8;
                hfrag[et] = *(const bf16x8*)(ph + ((e * 256 + k * 2) ^ ((e & 7) << 4)));
            }
#pragma unroll
            for (int ct = 0; ct < 2; ct++) {
                const int f = kt * 8 + (w * 2 + ct);
                const bf16x8 afrag = *(const bf16x8*)(W2p + (size_t)f * 512 + l * 8);
#pragma unroll
                for (int et = 0; et < 4; et++)
                    acc2[ct][et] = __builtin_amdgcn_mfma_f32_16x16x32_bf16(
                        afrag, hfrag[et], acc2[ct][et], 0, 0, 0);
            }
        }
        __syncthreads();   // before next path overwrites s_h
    }

    // ---- Attention: alpha[e][w] = sum_c p[e][c] * (acc2 + b2)[c] ----
    {
        float vsum[4] = {0.f, 0.f, 0.f, 0.f};
#pragma unroll
        for (int ct = 0; ct < 2; ct++) {
            const int c0 = w * 32 + ct * 16 + (l >> 4) * 4;
            const float4 br = *(const float4*)(b_rad2 + c0);
            const float4 bs = *(const float4*)(b_sph2 + c0);
#pragma unroll
            for (int et = 0; et < 4; et++) {
                const int e = et * 16 + (l & 15);
                const us4 pv = *(const us4*)(pp + ((e * 256 + c0 * 2) ^ ((e & 7) << 4)));
#pragma unroll
                for (int r = 0; r < 4; r++) {
                    const float wv = acc2[ct][et][r] + ((const float*)&br)[r]
                                                    + ((const float*)&bs)[r];
                    vsum[et] = fmaf(bf2f(pv[r]), wv, vsum[et]);
                }
            }
        }
#pragma unroll
        for (int et = 0; et < 4; et++) {
            float v = vsum[et];
            v += __shfl_xor(v, 16, 64);
            v += __shfl_xor(v, 32, 64);
            if (l < 16) {
                const int e = et * 16 + l;
                // 1/sqrt(32) * 1/32
                s_alpha[e][w] = v * cutoffs[eb + e] * 0.005524271728019903f;
            }
        }
    }
    __syncthreads();

    // ---- Scatter: msg = edge_sh * repeat(alpha, [1,3,5,7]); atomicAdd ----
    {
        const int e   = t >> 2;
        const int c0q = t & 3;
        const int eg  = eb + e;
        const int r   = receivers[eg];
        const float4 sh = *(const float4*)(edge_sh + (size_t)eg * 16 + c0q * 4);
#pragma unroll
        for (int j = 0; j < 4; j++) {
            const int comp = c0q * 4 + j;
            const int head = (comp == 0) ? 0 : (comp < 4) ? 1 : (comp < 9) ? 2 : 3;
            const float msg = ((const float*)&sh)[j] * s_alpha[e][head];
            atomicAdd(&out[(size_t)r * 16 + comp], msg);
        }
    }
}

// ---------------------------------------------------------------------------
extern "C" void kernel_launch(void* const* d_in, const int* in_sizes, int n_in,
                              void* d_out, int out_size, void* d_ws, size_t ws_size,
                              hipStream_t stream)
{
    const float* edge_sh    = (const float*)d_in[0];
    const float* node_feats = (const float*)d_in[1];
    const float* edge_feats = (const float*)d_in[2];
    const float* chi_scalar = (const float*)d_in[3];
    const float* cutoffs    = (const float*)d_in[4];
    const int*   senders    = (const int*)d_in[5];
    const int*   receivers  = (const int*)d_in[6];
    const float* W_rad1 = (const float*)d_in[7];
    const float* b_rad1 = (const float*)d_in[8];
    const float* W_rad2 = (const float*)d_in[9];
    const float* b_rad2 = (const float*)d_in[10];
    const float* W_sph1 = (const float*)d_in[11];
    const float* b_sph1 = (const float*)d_in[12];
    const float* W_sph2 = (const float*)d_in[13];
    const float* b_sph2 = (const float*)d_in[14];
    const float* Wq     = (const float*)d_in[15];
    const float* Wk     = (const float*)d_in[16];

    float* out  = (float*)d_out;
    float* qbuf = (float*)d_ws;                          // [N,128] fp32
    float* kbuf = qbuf + (size_t)NNODES * DDIM;          // [N,128] fp32
    unsigned short* pk = (unsigned short*)(kbuf + (size_t)NNODES * DDIM);
    unsigned short* w1r = pk;                            // 16 frames * 512
    unsigned short* w1s = w1r + 16 * 512;
    unsigned short* w2r = w1s + 16 * 512;                // 32 frames * 512
    unsigned short* w2s = w2r + 32 * 512;

    hipMemsetAsync(out, 0, (size_t)out_size * sizeof(float), stream);

    pack_weights<<<16, 256, 0, stream>>>(W_rad1, w1r);
    pack_weights<<<16, 256, 0, stream>>>(W_sph1, w1s);
    pack_weights<<<32, 256, 0, stream>>>(W_rad2, w2r);
    pack_weights<<<32, 256, 0, stream>>>(W_sph2, w2s);

    qk_proj_kernel<<<NNODES / TN, 256, 0, stream>>>(node_feats, Wq, Wk, qbuf, kbuf);

    edge_kernel<<<NEDGES / BE, 256, 0, stream>>>(
        edge_sh, cutoffs, senders, receivers, edge_feats, chi_scalar,
        w1r, w1s, w2r, w2s, b_rad1, b_sph1, b_rad2, b_sph2,
        qbuf, kbuf, out);
}